// Round 2
// baseline (438.344 us; speedup 1.0000x reference)
//
#include <hip/hip_runtime.h>
#include <math.h>

#define D 64
#define S 4

// ---------------- workspace layout (float offsets) ----------------
#define WS_KEYS 0      // keys[S][D]
#define WS_ST   256    // st_norm[S]
#define WS_SUMS 260    // uw_sums[S] (atomic, zeroed each launch)
#define WS_LW   264    // last_writer[S] (int, -1 init)
#define WS_OUT1 272    // out1[D] (16B aligned)

__global__ void k_prep(const float* __restrict__ slots,
                       const float* __restrict__ ss,
                       const float* __restrict__ Wk,
                       const float* __restrict__ bk,
                       float* __restrict__ ws) {
  int d = threadIdx.x;  // 64 threads
  __shared__ float sl[S][D];
  for (int s = 0; s < S; ++s) sl[s][d] = slots[s * D + d];
  __syncthreads();
  float bkd = bk[d];
  for (int s = 0; s < S; ++s) {
    float acc = bkd;
    for (int k = 0; k < D; ++k) acc = fmaf(sl[s][k], Wk[d * D + k], acc);
    ws[WS_KEYS + s * D + d] = tanhf(acc);
  }
  if (d < S) {
    ws[WS_SUMS + d] = 0.f;
    ((int*)ws)[WS_LW + d] = -1;
  }
  if (d == 0) {
    float st[S]; float tot = 0.f;
    for (int s = 0; s < S; ++s) {
      float x = ss[s];
      float sp = log1pf(expf(-fabsf(x))) + fmaxf(x, 0.f);  // softplus
      st[s] = sp; tot += sp;
    }
    for (int s = 0; s < S; ++s) ws[WS_ST + s] = st[s] / tot;
  }
}

// 2 rows per thread, 512 rows per block.
__launch_bounds__(256, 2)
__global__ void k_main(const float* __restrict__ item,
                       const float* __restrict__ Wq,
                       const float* __restrict__ bq,
                       float* ws,
                       float* __restrict__ slot_weights,
                       float* __restrict__ selected,
                       int B) {
  __shared__ float4 Wt4[D][16];   // Wt4[k][dq] = Wq^T[k][4dq..4dq+3]  (16 KB)
  __shared__ float4 keys4[S][16];
  __shared__ float4 bq4[16];
  __shared__ float  sts[S];
  __shared__ float  red_sum[4][S];
  __shared__ int    red_lw[4][S];

  int t = threadIdx.x;

  // stage Wq^T with CONSECUTIVE LDS addresses per lane (conflict-free writes);
  // global side is a transposed gather of a 16KB L2-resident matrix.
  for (int i = t; i < D * 16; i += 256) {     // 1024 float4s
    int k = i >> 4, dq = i & 15;
    float4 w;
    w.x = Wq[(dq * 4 + 0) * D + k];
    w.y = Wq[(dq * 4 + 1) * D + k];
    w.z = Wq[(dq * 4 + 2) * D + k];
    w.w = Wq[(dq * 4 + 3) * D + k];
    Wt4[k][dq] = w;
  }
  if (t < S * 16) keys4[t >> 4][t & 15] = ((const float4*)(ws + WS_KEYS))[t];
  if (t >= 64 && t < 80) bq4[t - 64] = ((const float4*)bq)[t - 64];
  if (t >= 80 && t < 80 + S) sts[t - 80] = ws[WS_ST + (t - 80)];
  __syncthreads();

  long b0 = (long)blockIdx.x * 512 + t;
  long b1 = b0 + 256;
  bool act0 = b0 < B, act1 = b1 < B;

  float a0[D], a1[D];
  #pragma unroll
  for (int dq = 0; dq < 16; ++dq) {
    float4 bb = bq4[dq];
    a0[4 * dq + 0] = bb.x; a0[4 * dq + 1] = bb.y;
    a0[4 * dq + 2] = bb.z; a0[4 * dq + 3] = bb.w;
    a1[4 * dq + 0] = bb.x; a1[4 * dq + 1] = bb.y;
    a1[4 * dq + 2] = bb.z; a1[4 * dq + 3] = bb.w;
  }

  const float4* r0 = (const float4*)(item + b0 * D);
  const float4* r1 = (const float4*)(item + b1 * D);
  float4 iv0, iv1;
  if (act0) iv0 = r0[0];
  if (act1) iv1 = r1[0];

  for (int kk = 0; kk < 16; ++kk) {   // NOT unrolled: keep code in I-cache
    float4 c0 = iv0, c1 = iv1;
    if (kk < 15) {                    // prefetch next 16B of each row
      if (act0) iv0 = r0[kk + 1];
      if (act1) iv1 = r1[kk + 1];
    }
    #pragma unroll
    for (int j = 0; j < 4; ++j) {
      float x0 = (j == 0) ? c0.x : (j == 1) ? c0.y : (j == 2) ? c0.z : c0.w;
      float x1 = (j == 0) ? c1.x : (j == 1) ? c1.y : (j == 2) ? c1.z : c1.w;
      int k = kk * 4 + j;
      #pragma unroll
      for (int dq = 0; dq < 16; ++dq) {
        float4 wv = Wt4[k][dq];       // wave-uniform broadcast read
        a0[4 * dq + 0] = fmaf(x0, wv.x, a0[4 * dq + 0]);
        a0[4 * dq + 1] = fmaf(x0, wv.y, a0[4 * dq + 1]);
        a0[4 * dq + 2] = fmaf(x0, wv.z, a0[4 * dq + 2]);
        a0[4 * dq + 3] = fmaf(x0, wv.w, a0[4 * dq + 3]);
        a1[4 * dq + 0] = fmaf(x1, wv.x, a1[4 * dq + 0]);
        a1[4 * dq + 1] = fmaf(x1, wv.y, a1[4 * dq + 1]);
        a1[4 * dq + 2] = fmaf(x1, wv.z, a1[4 * dq + 2]);
        a1[4 * dq + 3] = fmaf(x1, wv.w, a1[4 * dq + 3]);
      }
    }
  }

  #pragma unroll
  for (int d = 0; d < D; ++d) a0[d] = tanhf(a0[d]);
  #pragma unroll
  for (int d = 0; d < D; ++d) a1[d] = tanhf(a1[d]);

  float sim0[S], sim1[S];
  #pragma unroll
  for (int s = 0; s < S; ++s) {
    float p0 = 0.f, p1 = 0.f;
    #pragma unroll
    for (int dq = 0; dq < 16; ++dq) {
      float4 kv = keys4[s][dq];
      p0 = fmaf(a0[4 * dq + 0], kv.x, p0); p0 = fmaf(a0[4 * dq + 1], kv.y, p0);
      p0 = fmaf(a0[4 * dq + 2], kv.z, p0); p0 = fmaf(a0[4 * dq + 3], kv.w, p0);
      p1 = fmaf(a1[4 * dq + 0], kv.x, p1); p1 = fmaf(a1[4 * dq + 1], kv.y, p1);
      p1 = fmaf(a1[4 * dq + 2], kv.z, p1); p1 = fmaf(a1[4 * dq + 3], kv.w, p1);
    }
    sim0[s] = p0; sim1[s] = p1;
  }

  float u0[S], u1[S];
  int sel0 = 0, sel1 = 0;

  {
    float m = fmaxf(fmaxf(sim0[0], sim0[1]), fmaxf(sim0[2], sim0[3]));
    float e0 = expf(sim0[0] - m), e1 = expf(sim0[1] - m);
    float e2 = expf(sim0[2] - m), e3 = expf(sim0[3] - m);
    float se = e0 + e1 + e2 + e3;
    float w0 = e0 / se, w1 = e1 / se, w2 = e2 / se, w3 = e3 / se;
    if (act0) *(float4*)(slot_weights + b0 * S) = make_float4(w0, w1, w2, w3);
    u0[0] = w0 * sts[0]; u0[1] = w1 * sts[1]; u0[2] = w2 * sts[2]; u0[3] = w3 * sts[3];
    float us = u0[0] + u0[1] + u0[2] + u0[3];
    u0[0] /= us; u0[1] /= us; u0[2] /= us; u0[3] /= us;
    float best = u0[0];
    if (u0[1] > best) { best = u0[1]; sel0 = 1; }
    if (u0[2] > best) { best = u0[2]; sel0 = 2; }
    if (u0[3] > best) { best = u0[3]; sel0 = 3; }
    if (act0) selected[b0] = (float)sel0;
  }
  {
    float m = fmaxf(fmaxf(sim1[0], sim1[1]), fmaxf(sim1[2], sim1[3]));
    float e0 = expf(sim1[0] - m), e1 = expf(sim1[1] - m);
    float e2 = expf(sim1[2] - m), e3 = expf(sim1[3] - m);
    float se = e0 + e1 + e2 + e3;
    float w0 = e0 / se, w1 = e1 / se, w2 = e2 / se, w3 = e3 / se;
    if (act1) *(float4*)(slot_weights + b1 * S) = make_float4(w0, w1, w2, w3);
    u1[0] = w0 * sts[0]; u1[1] = w1 * sts[1]; u1[2] = w2 * sts[2]; u1[3] = w3 * sts[3];
    float us = u1[0] + u1[1] + u1[2] + u1[3];
    u1[0] /= us; u1[1] /= us; u1[2] /= us; u1[3] /= us;
    float best = u1[0];
    if (u1[1] > best) { best = u1[1]; sel1 = 1; }
    if (u1[2] > best) { best = u1[2]; sel1 = 2; }
    if (u1[3] > best) { best = u1[3]; sel1 = 3; }
    if (act1) selected[b1] = (float)sel1;
  }

  // ---- block reduction: uw sums (add) and last-writer (max) ----
  float r[S]; int l[S];
  #pragma unroll
  for (int s = 0; s < S; ++s) {
    r[s] = (act0 ? u0[s] : 0.f) + (act1 ? u1[s] : 0.f);
    l[s] = (act1 && sel1 == s) ? (int)b1 : ((act0 && sel0 == s) ? (int)b0 : -1);
  }
  #pragma unroll
  for (int off = 32; off > 0; off >>= 1) {
    #pragma unroll
    for (int s = 0; s < S; ++s) {
      r[s] += __shfl_down(r[s], off);
      int m = __shfl_down(l[s], off);
      l[s] = l[s] > m ? l[s] : m;
    }
  }
  int lane = t & 63, wid = t >> 6;
  if (lane == 0) {
    #pragma unroll
    for (int s = 0; s < S; ++s) { red_sum[wid][s] = r[s]; red_lw[wid][s] = l[s]; }
  }
  __syncthreads();
  if (t < S) {
    float tot = red_sum[0][t] + red_sum[1][t] + red_sum[2][t] + red_sum[3][t];
    atomicAdd(&ws[WS_SUMS + t], tot);
    int lm = red_lw[0][t];
    if (red_lw[1][t] > lm) lm = red_lw[1][t];
    if (red_lw[2][t] > lm) lm = red_lw[2][t];
    if (red_lw[3][t] > lm) lm = red_lw[3][t];
    atomicMax((int*)ws + WS_LW + t, lm);
  }
}

__global__ void k_final(const float* __restrict__ item,
                        const float* __restrict__ slots,
                        const float* __restrict__ usage,
                        const float* __restrict__ Wv,
                        const float* __restrict__ bv,
                        float* ws,
                        float* __restrict__ out_ns,
                        float* __restrict__ out_nu,
                        int B) {
  int d = threadIdx.x;  // 64 threads
  __shared__ float mean[D];
  const int* lw = (const int*)ws + WS_LW;
  float nsv[S];
  for (int s = 0; s < S; ++s) {
    int w = lw[s];
    float v = (w >= 0) ? item[(size_t)w * D + d] : slots[s * D + d];
    nsv[s] = v;
    out_ns[s * D + d] = v;
  }
  mean[d] = (nsv[0] + nsv[1] + nsv[2] + nsv[3]) * 0.25f;
  __syncthreads();
  float acc = bv[d];
  for (int k = 0; k < D; ++k) acc = fmaf(mean[k], Wv[d * D + k], acc);
  ws[WS_OUT1 + d] = tanhf(acc);
  if (d < S) out_nu[d] = usage[d] * 0.9f + ws[WS_SUMS + d] / (float)B;
}

__global__ void k_bcast(const float* __restrict__ ws,
                        float4* __restrict__ out, long n4) {
  __shared__ float4 o4[16];
  if (threadIdx.x < 16) o4[threadIdx.x] = ((const float4*)(ws + WS_OUT1))[threadIdx.x];
  __syncthreads();
  long i = (long)blockIdx.x * blockDim.x + threadIdx.x;
  long stride = (long)gridDim.x * blockDim.x;
  for (; i < n4; i += stride) out[i] = o4[i & 15];
}

extern "C" void kernel_launch(void* const* d_in, const int* in_sizes, int n_in,
                              void* d_out, int out_size, void* d_ws, size_t ws_size,
                              hipStream_t stream) {
  const float* item  = (const float*)d_in[0];
  const float* slots = (const float*)d_in[1];
  const float* ss    = (const float*)d_in[2];
  const float* usage = (const float*)d_in[3];
  const float* Wq    = (const float*)d_in[4];
  const float* bq    = (const float*)d_in[5];
  const float* Wk    = (const float*)d_in[6];
  const float* bk    = (const float*)d_in[7];
  const float* Wv    = (const float*)d_in[8];
  const float* bv    = (const float*)d_in[9];
  int B = in_sizes[0] / D;
  float* ws = (float*)d_ws;

  float* out_output       = (float*)d_out;
  float* out_new_slots    = out_output + (size_t)B * D;
  float* out_new_usage    = out_new_slots + S * D;
  float* out_selected     = out_new_usage + S;
  float* out_slot_weights = out_selected + B;

  k_prep<<<1, 64, 0, stream>>>(slots, ss, Wk, bk, ws);
  int blocks = (B + 511) / 512;
  k_main<<<blocks, 256, 0, stream>>>(item, Wq, bq, ws,
                                     out_slot_weights, out_selected, B);
  k_final<<<1, 64, 0, stream>>>(item, slots, usage, Wv, bv, ws,
                                out_new_slots, out_new_usage, B);
  long n4 = (long)B * D / 4;
  k_bcast<<<2048, 256, 0, stream>>>(ws, (float4*)out_output, n4);
}

// Round 3
// 183.815 us; speedup vs baseline: 2.3847x; 2.3847x over previous
//
#include <hip/hip_runtime.h>
#include <math.h>

#define D 64
#define S 4

// ---------------- workspace layout (float offsets) ----------------
#define WS_KEYS 0      // keys[S][D]
#define WS_ST   256    // st_norm[S]
#define WS_SUMS 260    // uw_sums[S] (atomic, zeroed each launch)
#define WS_LW   264    // last_writer[S] (int, -1 init)
#define WS_OUT1 272    // out1[D] (16B aligned)
#define WS_WQT  512    // WqT[k][d] = Wq[d][k], 64x64

__global__ void k_prep(const float* __restrict__ slots,
                       const float* __restrict__ ss,
                       const float* __restrict__ Wk,
                       const float* __restrict__ bk,
                       const float* __restrict__ Wq,
                       float* __restrict__ ws) {
  int d = threadIdx.x;  // 64 threads
  __shared__ float sl[S][D];
  for (int s = 0; s < S; ++s) sl[s][d] = slots[s * D + d];
  __syncthreads();
  float bkd = bk[d];
  for (int s = 0; s < S; ++s) {
    float acc = bkd;
    for (int k = 0; k < D; ++k) acc = fmaf(sl[s][k], Wk[d * D + k], acc);
    ws[WS_KEYS + s * D + d] = tanhf(acc);
  }
  // transpose Wq into ws: WqT[k][d] = Wq[d][k]  (coalesced writes)
  for (int k = 0; k < D; ++k) ws[WS_WQT + k * D + d] = Wq[d * D + k];
  if (d < S) {
    ws[WS_SUMS + d] = 0.f;
    ((int*)ws)[WS_LW + d] = -1;
  }
  if (d == 0) {
    float st[S]; float tot = 0.f;
    for (int s = 0; s < S; ++s) {
      float x = ss[s];
      float sp = log1pf(expf(-fabsf(x))) + fmaxf(x, 0.f);  // softplus
      st[s] = sp; tot += sp;
    }
    for (int s = 0; s < S; ++s) ws[WS_ST + s] = st[s] / tot;
  }
}

// 1 row/lane. W, keys, bq, st are wave-uniform -> scalar loads (SGPR), FMAs
// read SGPR src0 + VGPR src1. No LDS in the hot loop.
__launch_bounds__(256)
__global__ void k_main(const float* __restrict__ item,
                       const float* __restrict__ wqt,   // ws+WS_WQT
                       const float* __restrict__ keys,  // ws+WS_KEYS
                       const float* __restrict__ st4,   // ws+WS_ST
                       const float* __restrict__ bq,
                       float* red,                      // ws (atomics)
                       float* __restrict__ slot_weights,
                       float* __restrict__ selected,
                       int B) {
  __shared__ float red_sum[4][S];
  __shared__ int   red_lw[4][S];

  int t = threadIdx.x;
  long b = (long)blockIdx.x * 256 + t;
  bool act = b < B;

  float acc[D];
  #pragma unroll
  for (int dq = 0; dq < 16; ++dq) {
    float4 bb = *(const float4*)(bq + 4 * dq);   // uniform -> s_load
    acc[4 * dq + 0] = bb.x; acc[4 * dq + 1] = bb.y;
    acc[4 * dq + 2] = bb.z; acc[4 * dq + 3] = bb.w;
  }

  const float4* row = (const float4*)(item + b * D);
  float4 iv;
  if (act) iv = row[0];

  #pragma unroll 1
  for (int kk = 0; kk < 16; ++kk) {
    float4 cur = iv;
    if (kk < 15 && act) iv = row[kk + 1];        // prefetch next 16B
    #pragma unroll
    for (int j = 0; j < 4; ++j) {
      float x = (j == 0) ? cur.x : (j == 1) ? cur.y : (j == 2) ? cur.z : cur.w;
      const float* wrow = wqt + (kk * 4 + j) * D;
      #pragma unroll
      for (int dq = 0; dq < 16; ++dq) {
        float4 w = *(const float4*)(wrow + 4 * dq);  // uniform -> s_load
        acc[4 * dq + 0] = fmaf(x, w.x, acc[4 * dq + 0]);
        acc[4 * dq + 1] = fmaf(x, w.y, acc[4 * dq + 1]);
        acc[4 * dq + 2] = fmaf(x, w.z, acc[4 * dq + 2]);
        acc[4 * dq + 3] = fmaf(x, w.w, acc[4 * dq + 3]);
      }
    }
  }

  // fast tanh: 1 - 2*rcp(exp(2x)+1); correct at +/-inf saturation
  #pragma unroll
  for (int d = 0; d < D; ++d) {
    float e = __expf(2.f * acc[d]);
    acc[d] = fmaf(-2.f, __builtin_amdgcn_rcpf(e + 1.f), 1.f);
  }

  float sim[S];
  #pragma unroll
  for (int s = 0; s < S; ++s) {
    const float* krow = keys + s * D;
    float p = 0.f;
    #pragma unroll
    for (int dq = 0; dq < 16; ++dq) {
      float4 kv = *(const float4*)(krow + 4 * dq);  // uniform -> s_load
      p = fmaf(acc[4 * dq + 0], kv.x, p);
      p = fmaf(acc[4 * dq + 1], kv.y, p);
      p = fmaf(acc[4 * dq + 2], kv.z, p);
      p = fmaf(acc[4 * dq + 3], kv.w, p);
    }
    sim[s] = p;
  }

  float s0 = st4[0], s1 = st4[1], s2 = st4[2], s3 = st4[3];

  float u[S];
  int sel = 0;
  {
    float m = fmaxf(fmaxf(sim[0], sim[1]), fmaxf(sim[2], sim[3]));
    float e0 = expf(sim[0] - m), e1 = expf(sim[1] - m);
    float e2 = expf(sim[2] - m), e3 = expf(sim[3] - m);
    float se = e0 + e1 + e2 + e3;
    float w0 = e0 / se, w1 = e1 / se, w2 = e2 / se, w3 = e3 / se;
    if (act) *(float4*)(slot_weights + b * S) = make_float4(w0, w1, w2, w3);
    u[0] = w0 * s0; u[1] = w1 * s1; u[2] = w2 * s2; u[3] = w3 * s3;
    float us = u[0] + u[1] + u[2] + u[3];
    u[0] /= us; u[1] /= us; u[2] /= us; u[3] /= us;
    float best = u[0];
    if (u[1] > best) { best = u[1]; sel = 1; }
    if (u[2] > best) { best = u[2]; sel = 2; }
    if (u[3] > best) { best = u[3]; sel = 3; }
    if (act) selected[b] = (float)sel;
  }

  // ---- block reduction: uw sums (add) and last-writer (max) ----
  float r[S]; int l[S];
  #pragma unroll
  for (int s = 0; s < S; ++s) {
    r[s] = act ? u[s] : 0.f;
    l[s] = (act && sel == s) ? (int)b : -1;
  }
  #pragma unroll
  for (int off = 32; off > 0; off >>= 1) {
    #pragma unroll
    for (int s = 0; s < S; ++s) {
      r[s] += __shfl_down(r[s], off);
      int m = __shfl_down(l[s], off);
      l[s] = l[s] > m ? l[s] : m;
    }
  }
  int lane = t & 63, wid = t >> 6;
  if (lane == 0) {
    #pragma unroll
    for (int s = 0; s < S; ++s) { red_sum[wid][s] = r[s]; red_lw[wid][s] = l[s]; }
  }
  __syncthreads();
  if (t < S) {
    float tot = red_sum[0][t] + red_sum[1][t] + red_sum[2][t] + red_sum[3][t];
    atomicAdd(&red[WS_SUMS + t], tot);
    int lm = red_lw[0][t];
    if (red_lw[1][t] > lm) lm = red_lw[1][t];
    if (red_lw[2][t] > lm) lm = red_lw[2][t];
    if (red_lw[3][t] > lm) lm = red_lw[3][t];
    atomicMax((int*)red + WS_LW + t, lm);
  }
}

__global__ void k_final(const float* __restrict__ item,
                        const float* __restrict__ slots,
                        const float* __restrict__ usage,
                        const float* __restrict__ Wv,
                        const float* __restrict__ bv,
                        float* ws,
                        float* __restrict__ out_ns,
                        float* __restrict__ out_nu,
                        int B) {
  int d = threadIdx.x;  // 64 threads
  __shared__ float mean[D];
  const int* lw = (const int*)ws + WS_LW;
  float nsv[S];
  for (int s = 0; s < S; ++s) {
    int w = lw[s];
    float v = (w >= 0) ? item[(size_t)w * D + d] : slots[s * D + d];
    nsv[s] = v;
    out_ns[s * D + d] = v;
  }
  mean[d] = (nsv[0] + nsv[1] + nsv[2] + nsv[3]) * 0.25f;
  __syncthreads();
  float acc = bv[d];
  for (int k = 0; k < D; ++k) acc = fmaf(mean[k], Wv[d * D + k], acc);
  ws[WS_OUT1 + d] = tanhf(acc);
  if (d < S) out_nu[d] = usage[d] * 0.9f + ws[WS_SUMS + d] / (float)B;
}

__global__ void k_bcast(const float* __restrict__ ws,
                        float4* __restrict__ out, long n4) {
  __shared__ float4 o4[16];
  if (threadIdx.x < 16) o4[threadIdx.x] = ((const float4*)(ws + WS_OUT1))[threadIdx.x];
  __syncthreads();
  long i = (long)blockIdx.x * blockDim.x + threadIdx.x;
  long stride = (long)gridDim.x * blockDim.x;
  for (; i < n4; i += stride) out[i] = o4[i & 15];
}

extern "C" void kernel_launch(void* const* d_in, const int* in_sizes, int n_in,
                              void* d_out, int out_size, void* d_ws, size_t ws_size,
                              hipStream_t stream) {
  const float* item  = (const float*)d_in[0];
  const float* slots = (const float*)d_in[1];
  const float* ss    = (const float*)d_in[2];
  const float* usage = (const float*)d_in[3];
  const float* Wq    = (const float*)d_in[4];
  const float* bq    = (const float*)d_in[5];
  const float* Wk    = (const float*)d_in[6];
  const float* bk    = (const float*)d_in[7];
  const float* Wv    = (const float*)d_in[8];
  const float* bv    = (const float*)d_in[9];
  int B = in_sizes[0] / D;
  float* ws = (float*)d_ws;

  float* out_output       = (float*)d_out;
  float* out_new_slots    = out_output + (size_t)B * D;
  float* out_new_usage    = out_new_slots + S * D;
  float* out_selected     = out_new_usage + S;
  float* out_slot_weights = out_selected + B;

  k_prep<<<1, 64, 0, stream>>>(slots, ss, Wk, bk, Wq, ws);
  k_main<<<(B + 255) / 256, 256, 0, stream>>>(
      item, ws + WS_WQT, ws + WS_KEYS, ws + WS_ST, bq, ws,
      out_slot_weights, out_selected, B);
  k_final<<<1, 64, 0, stream>>>(item, slots, usage, Wv, bv, ws,
                                out_new_slots, out_new_usage, B);
  long n4 = (long)B * D / 4;
  k_bcast<<<2048, 256, 0, stream>>>(ws, (float4*)out_output, n4);
}